// Round 4
// baseline (67997.766 us; speedup 1.0000x reference)
//
#include <hip/hip_runtime.h>
#include <math.h>

// LSTM forward: T=1024, B=64, I=256, H=512 (4H=2048), fp32.
// Round 4: ONE persistent kernel (cooperative launch), 256 blocks x 512 thr.
//   block = (rg in [0,8): 8 batch rows) x (cg in [0,32): 16 cells = 64 gate cols)
//   thread = (wave wv in [0,8): 96-k chunk) x (lane in [0,64): gate col)
//   * weights: 96 fp32/thread in VGPRs, loaded ONCE (no per-step traffic)
//   * act (x_t || h_prev) staged 24KB/step in LDS, read as b128 broadcasts
//   * c: LDS-resident for all 1024 steps (never touches global)
//   * sync: per-ROW-GROUP barrier (32 blocks) via padded global counters,
//     release fence -> atomicAdd -> spin -> acquire fence (cross-XCD safe)
//   * h chains through d_out slots (natural double-buffer; d_out IS output)

#define TT      1024
#define BB      64
#define II      256
#define HH      512
#define G4H     2048
#define KT      768       // II + HH
#define RPB     8         // rows per block
#define CPB     16        // cells per block
#define JPB     64        // gate cols per block
#define NCG     32        // col groups
#define NRG     8         // row groups
#define THREADS 512
#define KC      96        // k-chunk per wave

__global__ void init_ctr(unsigned int* ctr) { ctr[threadIdx.x] = 0; }

__global__ __launch_bounds__(THREADS, 2) void lstm_persist(
    const float* __restrict__ x,    // [T][B][I]
    const float* __restrict__ Wi,   // [I][4H]
    const float* __restrict__ Wh,   // [H][4H]
    const float* __restrict__ bi,   // [4H]
    const float* __restrict__ bh,   // [4H]
    const float* __restrict__ h0,   // [B][H]
    const float* __restrict__ c0,   // [B][H]
    float* __restrict__ out,        // [T][B][H]
    unsigned int* __restrict__ ctr) // [NRG*32] padded, pre-zeroed
{
    const int tid  = threadIdx.x;
    const int cg   = blockIdx.x & 31;
    const int rg   = blockIdx.x >> 5;
    const int row0 = rg * RPB;
    const int cell0 = cg * CPB;

    const int lane = tid & 63;          // gate col within block
    const int wv   = tid >> 6;          // k-chunk id
    const int g    = lane >> 4;         // gate 0..3 (i,f,g,o)
    const int m    = lane & 15;         // cell within block
    const int J    = g * HH + cell0 + m; // global gate col

    __shared__ float act[RPB][KT];      // 24 KB: [r][0..256)=x, [256..768)=h
    __shared__ float red[8][RPB][JPB];  // 16 KB partial sums
    __shared__ float c_lds[RPB][CPB];   // cell state, persistent

    // ---- one-time: weights -> registers ----
    float4 w[KC / 4];
    #pragma unroll
    for (int kk4 = 0; kk4 < KC / 4; ++kk4) {
        float tmp[4];
        #pragma unroll
        for (int e = 0; e < 4; ++e) {
            const int k = wv * KC + kk4 * 4 + e;
            tmp[e] = (k < II) ? Wi[(size_t)k * G4H + J]
                              : Wh[(size_t)(k - II) * G4H + J];
        }
        w[kk4] = make_float4(tmp[0], tmp[1], tmp[2], tmp[3]);
    }
    const float bias = bi[J] + bh[J];

    // ---- one-time: c0 -> LDS (slot owner == updater, no sync needed) ----
    if (tid < RPB * CPB) {
        const int r = tid >> 4, mm = tid & 15;
        c_lds[r][mm] = c0[(size_t)(row0 + r) * HH + cell0 + mm];
    }

    unsigned int* myctr = ctr + rg * 32;  // padded counter line

    for (int t = 0; t < TT; ++t) {
        // ---- stage act = [x_t rows | h_{t-1} rows], coalesced ----
        {
            const float4* xb = (const float4*)(x + ((size_t)t * BB + row0) * II);
            const float4* hb = (const float4*)(
                ((t == 0) ? h0 : out + (size_t)(t - 1) * BB * HH)
                + (size_t)row0 * HH);
            float4* av = (float4*)&act[0][0];
            #pragma unroll
            for (int i = 0; i < 3; ++i) {
                const int s  = tid + THREADS * i;   // 0..1535
                const int r  = s / 192;
                const int c4 = s - r * 192;
                av[r * 192 + c4] = (c4 < 64) ? xb[r * 64 + c4]
                                             : hb[r * 128 + (c4 - 64)];
            }
        }
        __syncthreads();

        // ---- partial gates: 96-k chunk, 8 rows, weights in regs ----
        float acc[RPB];
        #pragma unroll
        for (int r = 0; r < RPB; ++r) acc[r] = 0.f;
        const float4* av = (const float4*)&act[0][0];
        const int abase = wv * (KC / 4);
        #pragma unroll
        for (int kk4 = 0; kk4 < KC / 4; ++kk4) {
            const float4 wk = w[kk4];
            #pragma unroll
            for (int r = 0; r < RPB; ++r) {
                const float4 a = av[r * 192 + abase + kk4];  // broadcast
                acc[r] = fmaf(a.x, wk.x, acc[r]);
                acc[r] = fmaf(a.y, wk.y, acc[r]);
                acc[r] = fmaf(a.z, wk.z, acc[r]);
                acc[r] = fmaf(a.w, wk.w, acc[r]);
            }
        }
        #pragma unroll
        for (int r = 0; r < RPB; ++r) red[wv][r][lane] = acc[r];
        __syncthreads();

        // ---- reduce 8 partials: thread's own (wv,lane) = output (r,jj) ----
        {
            float s = bias;
            #pragma unroll
            for (int p = 0; p < 8; ++p) s += red[p][wv][lane];
            red[0][wv][lane] = s;   // gbuf[r][jj]; own-slot rw, race-free
        }
        __syncthreads();

        // ---- cell update: 8 rows x 16 cells = 128 threads ----
        if (tid < RPB * CPB) {
            const int r  = tid >> 4;
            const int mm = tid & 15;
            float ig = red[0][r][0 * 16 + mm];
            float fg = red[0][r][1 * 16 + mm];
            float gg = red[0][r][2 * 16 + mm];
            float og = red[0][r][3 * 16 + mm];
            ig = 1.0f / (1.0f + __expf(-ig));
            fg = 1.0f / (1.0f + __expf(-fg));
            og = 1.0f / (1.0f + __expf(-og));
            gg = tanhf(gg);
            const float cn = fg * c_lds[r][mm] + ig * gg;
            c_lds[r][mm] = cn;
            out[((size_t)t * BB + row0 + r) * HH + cell0 + mm] = og * tanhf(cn);
        }

        // ---- row-group barrier: release -> arrive -> spin -> acquire ----
        __threadfence();      // release: h stores visible at device scope
        __syncthreads();      // all waves' fences done before arrive
        if (tid == 0) {
            __hip_atomic_fetch_add(myctr, 1u, __ATOMIC_RELAXED,
                                   __HIP_MEMORY_SCOPE_AGENT);
            const unsigned int target = 32u * (unsigned int)(t + 1);
            while (__hip_atomic_load(myctr, __ATOMIC_RELAXED,
                                     __HIP_MEMORY_SCOPE_AGENT) < target) {
                __builtin_amdgcn_s_sleep(2);
            }
        }
        __syncthreads();      // all waves wait for arrival
        __threadfence();      // acquire: invalidate stale cached h lines
    }
}

extern "C" void kernel_launch(void* const* d_in, const int* in_sizes, int n_in,
                              void* d_out, int out_size, void* d_ws, size_t ws_size,
                              hipStream_t stream) {
    const float* x  = (const float*)d_in[0];
    const float* Wi = (const float*)d_in[1];
    const float* Wh = (const float*)d_in[2];
    const float* bi = (const float*)d_in[3];
    const float* bh = (const float*)d_in[4];
    const float* h0 = (const float*)d_in[5];
    const float* c0 = (const float*)d_in[6];
    float* out = (float*)d_out;
    unsigned int* ctr = (unsigned int*)d_ws;   // 256 uints = 1 KB

    init_ctr<<<1, 256, 0, stream>>>(ctr);

    void* args[] = { (void*)&x, (void*)&Wi, (void*)&Wh, (void*)&bi,
                     (void*)&bh, (void*)&h0, (void*)&c0, (void*)&out,
                     (void*)&ctr };
    hipError_t e = hipLaunchCooperativeKernel((const void*)lstm_persist,
                                              dim3(NRG * NCG), dim3(THREADS),
                                              args, 0, stream);
    if (e != hipSuccess) {
        (void)hipGetLastError();   // clear; fall back to plain launch
        // 256 blocks == CU count with 1-block/CU resources: breadth-first
        // dispatch co-residency (barrier is per-32-block row group only).
        lstm_persist<<<dim3(NRG * NCG), dim3(THREADS), 0, stream>>>(
            x, Wi, Wh, bi, bh, h0, c0, out, ctr);
    }
}

// Round 6
// 6825.479 us; speedup vs baseline: 9.9623x; 9.9623x over previous
//
#include <hip/hip_runtime.h>
#include <math.h>

// LSTM forward: T=1024, B=64, I=256, H=512 (4H=2048), fp32.
// Round 6: persistent kernel (R5 structure) with HARDWARE-EXPLICIT ordering:
//   * h exchange via inline-asm global ops with sc0 sc1 (L1/L2 bypass -> IF$)
//   * explicit per-wave "s_waitcnt vmcnt(0)" drain before the arrive barrier
//     (R5 relied on __syncthreads' implicit drain -- suspected elided)
//   * row-group (32-block) spin barrier on relaxed agent atomics
// block = (rg: 8 rows) x (cg: 16 cells = 64 gate cols); 256 blocks x 512 thr.
// weights: 96 f32/thread in VGPRs loaded once; c LDS-resident; h via d_out.

#define TT      1024
#define BB      64
#define II      256
#define HH      512
#define G4H     2048
#define KT      768
#define RPB     8
#define CPB     16
#define NCG     32
#define NRG     8
#define THREADS 512
#define KC      48

__device__ __forceinline__ void coh_load2_f4(const float* p0, const float* p1,
                                             float4& a, float4& b) {
    asm volatile(
        "global_load_dwordx4 %0, %2, off sc0 sc1\n\t"
        "global_load_dwordx4 %1, %3, off sc0 sc1\n\t"
        "s_waitcnt vmcnt(0)"
        : "=&v"(a), "=&v"(b)
        : "v"(p0), "v"(p1)
        : "memory");
}
__device__ __forceinline__ void coh_store_f(float* p, float v) {
    asm volatile("global_store_dword %0, %1, off sc0 sc1"
                 :: "v"(p), "v"(v) : "memory");
}

__global__ void init_ctr(unsigned int* ctr) { ctr[threadIdx.x] = 0; }

__global__ __launch_bounds__(THREADS, 2) void lstm_persist(
    const float* __restrict__ x,    // [T][B][I]
    const float* __restrict__ Wi,   // [I][4H]
    const float* __restrict__ Wh,   // [H][4H]
    const float* __restrict__ bi,   // [4H]
    const float* __restrict__ bh,   // [4H]
    const float* __restrict__ h0,   // [B][H]
    const float* __restrict__ c0,   // [B][H]
    float* __restrict__ out,        // [T][B][H]
    unsigned int* __restrict__ ctr) // [NRG*32], pre-zeroed
{
    const int tid   = threadIdx.x;
    const int cg    = blockIdx.x & 31;
    const int rg    = blockIdx.x >> 5;
    const int row0  = rg * RPB;
    const int cell0 = cg * CPB;

    const int lane   = tid & 63;
    const int wv     = tid >> 6;
    const int colgrp = lane & 31;
    const int kc     = wv * 2 + (lane >> 5);   // k chunk 0..15

    const int bcA = colgrp, bcB = colgrp + 32;
    const int JA  = (bcA >> 4) * HH + cell0 + (bcA & 15);
    const int JB  = (bcB >> 4) * HH + cell0 + (bcB & 15);

    const int fr = tid >> 6;                   // assembly row
    const int fj = tid & 63;                   // assembly col
    const int Jf = (fj >> 4) * HH + cell0 + (fj & 15);
    const float biasf = bi[Jf] + bh[Jf];

    __shared__ float act[RPB][KT];             // 24 KB
    __shared__ float red[8][RPB][64];          // 16 KB
    __shared__ float gbuf[RPB][64];            // 2 KB
    __shared__ float c_lds[RPB][CPB];          // 512 B, persistent

    // ---- one-time: weights -> VGPRs (2 cols x 48 k = 96 f32) ----
    float4 wA[KC / 4], wB[KC / 4];
    #pragma unroll
    for (int q = 0; q < KC / 4; ++q) {
        float ta[4], tb[4];
        #pragma unroll
        for (int e = 0; e < 4; ++e) {
            const int k = kc * KC + q * 4 + e;
            ta[e] = (k < II) ? Wi[(size_t)k * G4H + JA]
                             : Wh[(size_t)(k - II) * G4H + JA];
            tb[e] = (k < II) ? Wi[(size_t)k * G4H + JB]
                             : Wh[(size_t)(k - II) * G4H + JB];
        }
        wA[q] = make_float4(ta[0], ta[1], ta[2], ta[3]);
        wB[q] = make_float4(tb[0], tb[1], tb[2], tb[3]);
    }

    // ---- one-time: c0 -> LDS (slot writer == slot reader, no sync) ----
    if (tid < RPB * CPB) {
        const int r = tid >> 4, m = tid & 15;
        c_lds[r][m] = c0[(size_t)(row0 + r) * HH + cell0 + m];
    }

    unsigned int* myctr = ctr + rg * 32;

    for (int t = 0; t < TT; ++t) {
        // ---- stage x (plain) + h_prev (coherent bypass dwordx4) ----
        const float4 xv = ((const float4*)(x + ((size_t)t * BB + row0) * II))
                              [(tid >> 6) * 64 + (tid & 63)];
        const float* hbase = ((t == 0) ? h0 : out + (size_t)(t - 1) * BB * HH)
                             + (size_t)row0 * HH;
        float4 ha, hb;
        coh_load2_f4(hbase + (size_t)tid * 8, hbase + (size_t)tid * 8 + 4,
                     ha, hb);

        ((float4*)&act[0][0])[(tid >> 6) * (KT / 4) + (tid & 63)] = xv;
        {   // wave w stages row w's h: act[w][II + lane*8 ..]
            float4* hd = (float4*)&act[tid >> 6][II + (tid & 63) * 8];
            hd[0] = ha; hd[1] = hb;
        }
        __syncthreads();

        // ---- partial gates: 2 cols x 48 k x 8 rows, weights in regs ----
        float accA[RPB], accB[RPB];
        #pragma unroll
        for (int r = 0; r < RPB; ++r) { accA[r] = 0.f; accB[r] = 0.f; }
        const float4* av = ((const float4*)&act[0][0]) + kc * (KC / 4);
        #pragma unroll
        for (int q = 0; q < KC / 4; ++q) {
            const float4 wa = wA[q], wb = wB[q];
            #pragma unroll
            for (int r = 0; r < RPB; ++r) {
                const float4 a = av[r * (KT / 4) + q];   // wave-uniform bcast
                accA[r] = fmaf(a.x, wa.x, accA[r]);
                accA[r] = fmaf(a.y, wa.y, accA[r]);
                accA[r] = fmaf(a.z, wa.z, accA[r]);
                accA[r] = fmaf(a.w, wa.w, accA[r]);
                accB[r] = fmaf(a.x, wb.x, accB[r]);
                accB[r] = fmaf(a.y, wb.y, accB[r]);
                accB[r] = fmaf(a.z, wb.z, accB[r]);
                accB[r] = fmaf(a.w, wb.w, accB[r]);
            }
        }
        #pragma unroll
        for (int r = 0; r < RPB; ++r) {       // pair (kc, kc^1) at lane^32
            accA[r] += __shfl_xor(accA[r], 32, 64);
            accB[r] += __shfl_xor(accB[r], 32, 64);
        }
        if (lane < 32) {
            #pragma unroll
            for (int r = 0; r < RPB; ++r) {
                red[wv][r][colgrp]      = accA[r];
                red[wv][r][colgrp + 32] = accB[r];
            }
        }
        __syncthreads();

        // ---- assemble gates: thread = (fr, fj) ----
        {
            float s = biasf;
            #pragma unroll
            for (int p = 0; p < 8; ++p) s += red[p][fr][fj];
            gbuf[fr][fj] = s;
        }
        __syncthreads();

        // ---- cell update: 8 rows x 16 cells ----
        if (tid < RPB * CPB) {
            const int r = tid >> 4, m = tid & 15;
            float ig = gbuf[r][ 0 + m];
            float fg = gbuf[r][16 + m];
            float gg = gbuf[r][32 + m];
            float og = gbuf[r][48 + m];
            ig = 1.0f / (1.0f + __expf(-ig));
            fg = 1.0f / (1.0f + __expf(-fg));
            og = 1.0f / (1.0f + __expf(-og));
            gg = tanhf(gg);
            const float cn = fg * c_lds[r][m] + ig * gg;
            c_lds[r][m] = cn;
            const size_t idx = ((size_t)t * BB + row0 + r) * HH + cell0 + m;
            coh_store_f(out + idx, og * tanhf(cn));
        }

        // ---- row-group barrier with EXPLICIT hardware drain ----
        asm volatile("s_waitcnt vmcnt(0) lgkmcnt(0)" ::: "memory");
        __syncthreads();     // all waves drained before arrive
        if (tid == 0) {
            __hip_atomic_fetch_add(myctr, 1u, __ATOMIC_RELAXED,
                                   __HIP_MEMORY_SCOPE_AGENT);
            const unsigned int target = 32u * (unsigned int)(t + 1);
            while (__hip_atomic_load(myctr, __ATOMIC_RELAXED,
                                     __HIP_MEMORY_SCOPE_AGENT) < target) {
                __builtin_amdgcn_s_sleep(2);
            }
            asm volatile("s_waitcnt vmcnt(0) lgkmcnt(0)" ::: "memory");
        }
        __syncthreads();
    }
}

extern "C" void kernel_launch(void* const* d_in, const int* in_sizes, int n_in,
                              void* d_out, int out_size, void* d_ws, size_t ws_size,
                              hipStream_t stream) {
    const float* x  = (const float*)d_in[0];
    const float* Wi = (const float*)d_in[1];
    const float* Wh = (const float*)d_in[2];
    const float* bi = (const float*)d_in[3];
    const float* bh = (const float*)d_in[4];
    const float* h0 = (const float*)d_in[5];
    const float* c0 = (const float*)d_in[6];
    float* out = (float*)d_out;
    unsigned int* ctr = (unsigned int*)d_ws;   // 256 uints

    init_ctr<<<1, 256, 0, stream>>>(ctr);

    void* args[] = { (void*)&x, (void*)&Wi, (void*)&Wh, (void*)&bi,
                     (void*)&bh, (void*)&h0, (void*)&c0, (void*)&out,
                     (void*)&ctr };
    hipError_t e = hipLaunchCooperativeKernel((const void*)lstm_persist,
                                              dim3(NRG * NCG), dim3(THREADS),
                                              args, 0, stream);
    if (e != hipSuccess) {
        (void)hipGetLastError();
        // barrier is per-contiguous-32-block row group; 256 blocks at
        // 1 block/CU co-reside even with plain dispatch
        lstm_persist<<<dim3(NRG * NCG), dim3(THREADS), 0, stream>>>(
            x, Wi, Wh, bi, bh, h0, c0, out, ctr);
    }
}